// Round 1
// 1432.157 us; speedup vs baseline: 1.1954x; 1.1954x over previous
//
#include <hip/hip_runtime.h>
#include <stdint.h>
#include <math.h>

typedef unsigned short u16;
typedef unsigned int u32;
using short8 = __attribute__((ext_vector_type(8))) short;
using f32x4  = __attribute__((ext_vector_type(4))) float;

#define NHEADS 12
#define NTOK 49
#define CDIM 384
#define HIDDIM 1536
#define HDIM 32
#define BNWIN 2048                 // 32 batches * 64 windows
#define MROWS 100352               // BNWIN * NTOK
#define QKV_STRIDE ((size_t)BNWIN * NHEADS * NTOK * HDIM)   // 38535168 elems
#define ATT_SCALE 0.17677669529663687f
#define AW 4                       // waves per attention block

__device__ __forceinline__ float bf2f(u16 u) {
    union { unsigned int i; float f; } z; z.i = ((unsigned int)u) << 16; return z.f;
}
__device__ __forceinline__ u16 f2bf(float f) {
    union { float f; unsigned int i; } z; z.f = f;
    unsigned int i = z.i;
    i += 0x7FFFu + ((i >> 16) & 1u);   // round-to-nearest-even
    return (u16)(i >> 16);
}
__device__ __forceinline__ float lo16(u32 u) {
    union { u32 i; float f; } z; z.i = u << 16; return z.f;
}
__device__ __forceinline__ float hi16(u32 u) {
    union { u32 i; float f; } z; z.i = u & 0xffff0000u; return z.f;
}

__device__ __forceinline__ void async16(const void* g, void* l) {
    __builtin_amdgcn_global_load_lds(
        (const __attribute__((address_space(1))) void*)g,
        (__attribute__((address_space(3))) void*)l, 16, 0, 0);
}

// ---------------- weight convert+transpose: B_f32[K][N] -> BT_bf16[N][K] -------
__global__ __launch_bounds__(256) void k_conv(const float* __restrict__ B,
    u16* __restrict__ BT, int K, int N)
{
    const int idx = blockIdx.x * 256 + threadIdx.x;
    if (idx >= K * N) return;
    const int n = idx / K, k = idx - n * K;
    BT[idx] = f2bf(B[(size_t)k * N + n]);
}

// ---------------- bias+mask table in MFMA D-fragment layout --------------------
// layout: [cls(4)][head(12)][tile mt*4+nt (16)][lane (64)][reg r (4)] f32
//   key  = mt*16 + (lane>>4)*4 + r   (S^T row)
//   query= nt*16 + (lane&15)         (S^T col)
// key>=49 -> -1e30 (pad mask), query>=49 -> 0 (discarded)
__global__ __launch_bounds__(256) void k_btab(const float* __restrict__ rpb,
    float* __restrict__ bt)
{
    const int idx = blockIdx.x * 256 + threadIdx.x;   // < 4*12*4096 = 196608
    const int r    = idx & 3;
    const int lane = (idx >> 2) & 63;
    const int tile = (idx >> 8) & 15;
    const int h    = (idx >> 12) % NHEADS;
    const int cls  = idx / (NHEADS << 12);
    const int mt = tile >> 2, nt = tile & 3;
    const int kt = mt * 16 + (lane >> 4) * 4 + r;
    const int qt = nt * 16 + (lane & 15);
    float val;
    if (kt >= NTOK) val = -1e30f;
    else if (qt >= NTOK) val = 0.f;
    else {
        const int pk = kt / 7, qk = kt % 7, pq = qt / 7, qq = qt % 7;
        val = rpb[((pq - pk + 6) * 13 + (qq - qk + 6)) * NHEADS + h];
        const int ae = cls >> 1, be = cls & 1;
        const int regq = (ae ? ((pq < 4) ? 1 : 2) : 0) * 3 + (be ? ((qq < 4) ? 1 : 2) : 0);
        const int regk = (ae ? ((pk < 4) ? 1 : 2) : 0) * 3 + (be ? ((qk < 4) ? 1 : 2) : 0);
        if (regq != regk) val -= 100.f;
    }
    bt[idx] = val;
}

// ---------------- LN1 + roll(-3,-3) + window partition (gather) ----------------
__global__ __launch_bounds__(256) void k_ln1(const float* __restrict__ x,
    const float* __restrict__ g, const float* __restrict__ b, u16* __restrict__ outw)
{
    const int lane = threadIdx.x & 63;
    const int t = blockIdx.x * 4 + (threadIdx.x >> 6);     // 0..100351
    const int wi = t / NTOK, n = t % NTOK;
    const int bb = wi >> 6, w64 = wi & 63;
    const int p = (w64 >> 3) * 7 + n / 7;
    const int q = (w64 & 7) * 7 + n % 7;
    const int sh = (p + 3) % 56, sw = (q + 3) % 56;        // roll by -3
    const float* row = x + ((size_t)bb * 3136 + sh * 56 + sw) * CDIM;
    float v[6]; float s = 0.f, sq = 0.f;
#pragma unroll
    for (int i = 0; i < 6; i++) {
        v[i] = row[lane + 64 * i];
        s += v[i]; sq += v[i] * v[i];
    }
#pragma unroll
    for (int off = 32; off >= 1; off >>= 1) {
        s  += __shfl_xor(s, off, 64);
        sq += __shfl_xor(sq, off, 64);
    }
    const float mean = s * (1.f / CDIM);
    const float var  = sq * (1.f / CDIM) - mean * mean;
    const float rstd = rsqrtf(var + 1e-5f);
    u16* orow = outw + (size_t)t * CDIM;
#pragma unroll
    for (int i = 0; i < 6; i++) {
        const int c = lane + 64 * i;
        orow[c] = f2bf((v[i] - mean) * rstd * g[c] + b[c]);
    }
}

// ---------------- LN2 (straight rows, fp32 input from d_out, bf16 out) ---------
__global__ __launch_bounds__(256) void k_ln2(const float* __restrict__ y,
    const float* __restrict__ g, const float* __restrict__ b, u16* __restrict__ outw)
{
    const int lane = threadIdx.x & 63;
    const int t = blockIdx.x * 4 + (threadIdx.x >> 6);
    const float* row = y + (size_t)t * CDIM;
    float v[6]; float s = 0.f, sq = 0.f;
#pragma unroll
    for (int i = 0; i < 6; i++) {
        v[i] = row[lane + 64 * i];
        s += v[i]; sq += v[i] * v[i];
    }
#pragma unroll
    for (int off = 32; off >= 1; off >>= 1) {
        s  += __shfl_xor(s, off, 64);
        sq += __shfl_xor(sq, off, 64);
    }
    const float mean = s * (1.f / CDIM);
    const float var  = sq * (1.f / CDIM) - mean * mean;
    const float rstd = rsqrtf(var + 1e-5f);
    u16* orow = outw + (size_t)t * CDIM;
#pragma unroll
    for (int i = 0; i < 6; i++) {
        const int c = lane + 64 * i;
        orow[c] = f2bf((v[i] - mean) * rstd * g[c] + b[c]);
    }
}

// ---------------- MFMA GEMM: C = A_bf16(MxK) * BT_bf16(N x K)^T + bias ---------
template<int MODE>
__global__ __launch_bounds__(256) void k_mgemm(
    const u16* __restrict__ A, const u16* __restrict__ BT,
    const float* __restrict__ bias,
    u16* __restrict__ out_bf,
    const float* res_f,
    float* out_f,
    int M, int Nn, int K)
{
    __shared__ __align__(16) u16 Als[128 * 32];
    __shared__ __align__(16) u16 Bls[128 * 32];
    const int tid = threadIdx.x;
    const int w = tid >> 6, l = tid & 63;
    const int wr = w >> 1, wc = w & 1;
    const int lrow = l & 15, quad = l >> 4;
    const int m0 = blockIdx.x * 128, n0 = blockIdx.y * 128;

    const int seg0 = tid, seg1 = tid + 256;
    const int r0 = seg0 >> 2, q0 = (seg0 & 3) ^ ((r0 >> 1) & 3);
    const int r1 = seg1 >> 2, q1 = (seg1 & 3) ^ ((r1 >> 1) & 3);
    const u16* Ag0 = A  + (size_t)(m0 + r0) * K + q0 * 8;
    const u16* Ag1 = A  + (size_t)(m0 + r1) * K + q1 * 8;
    const u16* Bg0 = BT + (size_t)(n0 + r0) * K + q0 * 8;
    const u16* Bg1 = BT + (size_t)(n0 + r1) * K + q1 * 8;
    u16* Al0 = &Als[seg0 * 8]; u16* Al1 = &Als[seg1 * 8];
    u16* Bl0 = &Bls[seg0 * 8]; u16* Bl1 = &Bls[seg1 * 8];

    const short8* afp[4]; const short8* bfp[4];
#pragma unroll
    for (int i = 0; i < 4; i++) {
        const int ra = wr * 64 + i * 16 + lrow;
        afp[i] = (const short8*)&Als[ra * 32 + ((quad ^ ((ra >> 1) & 3)) << 3)];
        const int rb = wc * 64 + i * 16 + lrow;
        bfp[i] = (const short8*)&Bls[rb * 32 + ((quad ^ ((rb >> 1) & 3)) << 3)];
    }

    f32x4 acc[4][4];
#pragma unroll
    for (int i = 0; i < 4; i++)
#pragma unroll
        for (int j = 0; j < 4; j++)
            acc[i][j] = (f32x4){0.f, 0.f, 0.f, 0.f};

    for (int k0 = 0; k0 < K; k0 += 32) {
        async16(Ag0 + k0, Al0);
        async16(Ag1 + k0, Al1);
        async16(Bg0 + k0, Bl0);
        async16(Bg1 + k0, Bl1);
        __syncthreads();
        short8 af[4], bf[4];
#pragma unroll
        for (int i = 0; i < 4; i++) { af[i] = *afp[i]; bf[i] = *bfp[i]; }
#pragma unroll
        for (int mi = 0; mi < 4; mi++)
#pragma unroll
            for (int ni = 0; ni < 4; ni++)
                acc[mi][ni] = __builtin_amdgcn_mfma_f32_16x16x32_bf16(
                    af[mi], bf[ni], acc[mi][ni], 0, 0, 0);
        __syncthreads();
    }

    const int mbase = m0 + wr * 64 + quad * 4;
    const int nbase = n0 + wc * 64 + lrow;
#pragma unroll
    for (int mi = 0; mi < 4; mi++) {
#pragma unroll
        for (int r = 0; r < 4; r++) {
            const int grow = mbase + mi * 16 + r;
            if constexpr (MODE == 0) {
                const int wi = grow / NTOK, n = grow % NTOK;
#pragma unroll
                for (int ni = 0; ni < 4; ni++) {
                    const int gcol = nbase + ni * 16;
                    float val = acc[mi][ni][r] + bias[gcol];
                    const int part = gcol / CDIM;
                    const int rem = gcol % CDIM;
                    const int hcol = rem >> 5, d = rem & 31;
                    if (part == 0) val *= ATT_SCALE;
                    out_bf[(size_t)part * QKV_STRIDE +
                           (((size_t)wi * NHEADS + hcol) * NTOK + n) * HDIM + d] = f2bf(val);
                }
            } else if constexpr (MODE == 1) {
                const int wi = grow / NTOK, n = grow % NTOK;
                const int bb = wi >> 6, w64 = wi & 63;
                const int p = (w64 >> 3) * 7 + n / 7;
                const int q = (w64 & 7) * 7 + n % 7;
                const int sh = (p + 3) % 56, sw = (q + 3) % 56;
                const size_t drow = ((size_t)bb * 3136 + sh * 56 + sw) * CDIM;
#pragma unroll
                for (int ni = 0; ni < 4; ni++) {
                    const int gcol = nbase + ni * 16;
                    out_f[drow + gcol] = res_f[drow + gcol] + acc[mi][ni][r] + bias[gcol];
                }
            } else if constexpr (MODE == 2) {
#pragma unroll
                for (int ni = 0; ni < 4; ni++) {
                    const int gcol = nbase + ni * 16;
                    const float v = acc[mi][ni][r] + bias[gcol];
                    const float gel = 0.5f * v * (1.0f + erff(v * 0.70710678118654752f));
                    out_bf[(size_t)grow * Nn + gcol] = f2bf(gel);
                }
            } else {  // MODE 3
#pragma unroll
                for (int ni = 0; ni < 4; ni++) {
                    const int gcol = nbase + ni * 16;
                    const size_t o = (size_t)grow * Nn + gcol;
                    out_f[o] = acc[mi][ni][r] + bias[gcol] + res_f[o];
                }
            }
        }
    }
}

// ---------------- MFMA windowed attention ---------------------------------------
// One wave per (window, head); AW waves/block. 49 tokens padded to 64.
// S^T = mfma(K, Q) with bias+mask table as C-in (table pre-masks key padding).
// Softmax over keys = 16 in-lane values + 2 shfl_xor per query group.
// O^T = mfma(V^T, P^T): V transposed+zero-padded into swizzled LDS, P bounced
// through swizzled LDS as bf16.
// LDS/wave: Vt 4KB + P 8KB -> 48KB/block -> 3 blocks/CU (12 waves/CU).
__global__ __launch_bounds__(64 * AW) void k_attn2(
    const u16* __restrict__ qkv, const float* __restrict__ btab,
    u16* __restrict__ ctx)
{
    __shared__ __align__(16) u16 Vt[AW][2048];   // V^T [d=32][key=64], swizzled
    __shared__ __align__(16) u16 Pl[AW][4096];   // P  [q=64][key=64], swizzled

    const int wv = threadIdx.x >> 6, lane = threadIdx.x & 63;
    const int quad = lane >> 4, c16 = lane & 15;
    const int gwh = blockIdx.x * AW + wv;        // 0..24575 == wi*12 + h
    const int wi = gwh / NHEADS, h = gwh - wi * NHEADS;
    const u16* qb = qkv + (size_t)gwh * (NTOK * HDIM);
    const u16* kb = qb + QKV_STRIDE;
    const u16* vb = qb + 2 * QKV_STRIDE;

    // ---- stage V transposed + zero-padded (keys 49..63 -> 0) into swizzled LDS
    // swizzle: idx = (d*64 + t) ^ ((d&7)<<3) ^ (((d>>3)&3)<<4)  (flips t bits 3..5)
    u16* vt = &Vt[wv][0];
    for (int i = lane; i < 256; i += 64) {
        const int tok = i >> 2, d0 = (i & 3) * 8;
        uint4 t = make_uint4(0u, 0u, 0u, 0u);
        if (tok < NTOK) t = *(const uint4*)(vb + tok * HDIM + d0);
        const u32 w_[4] = { t.x, t.y, t.z, t.w };
#pragma unroll
        for (int j = 0; j < 8; j++) {
            const int d = d0 + j;
            const u16 val = (u16)((j & 1) ? (w_[j >> 1] >> 16) : (w_[j >> 1] & 0xffffu));
            vt[(d * 64 + tok) ^ ((d & 7) << 3) ^ (((d >> 3) & 3) << 4)] = val;
        }
    }

    // ---- Q,K fragments direct from global (rows >=49 read neighbor data; masked)
    short8 qf[4], kf[4];
#pragma unroll
    for (int t = 0; t < 4; t++) {
        qf[t] = *(const short8*)(qb + (t * 16 + c16) * HDIM + quad * 8);
        kf[t] = *(const short8*)(kb + (t * 16 + c16) * HDIM + quad * 8);
    }

    // ---- bias+mask table slice (fragment-layout, used as MFMA C-in)
    const int a = (wi & 63) >> 3, b = wi & 7;
    const int cls = ((a == 7) ? 2 : 0) | ((b == 7) ? 1 : 0);
    const f32x4* tb = (const f32x4*)(btab + ((size_t)(cls * NHEADS + h) << 12));

    // ---- S^T = K * Q^T + (bias+mask): D row = key (quad*4+r), col = query (c16)
    f32x4 acc[4][4];
#pragma unroll
    for (int mt = 0; mt < 4; mt++)
#pragma unroll
        for (int nt = 0; nt < 4; nt++)
            acc[mt][nt] = __builtin_amdgcn_mfma_f32_16x16x32_bf16(
                kf[mt], qf[nt], tb[(mt * 4 + nt) * 64 + lane], 0, 0, 0);

    // ---- softmax over keys (rows of S^T): in-lane (4 mt * 4 r) + quads via shfl
    float inv[4];
#pragma unroll
    for (int nt = 0; nt < 4; nt++) {
        float m = -1e30f;
#pragma unroll
        for (int mt = 0; mt < 4; mt++)
#pragma unroll
            for (int r = 0; r < 4; r++) m = fmaxf(m, acc[mt][nt][r]);
        m = fmaxf(m, __shfl_xor(m, 16, 64));
        m = fmaxf(m, __shfl_xor(m, 32, 64));
        float s = 0.f;
#pragma unroll
        for (int mt = 0; mt < 4; mt++)
#pragma unroll
            for (int r = 0; r < 4; r++) {
                const float e = __expf(acc[mt][nt][r] - m);
                acc[mt][nt][r] = e;
                s += e;
            }
        s += __shfl_xor(s, 16, 64);
        s += __shfl_xor(s, 32, 64);
        inv[nt] = 1.f / s;
    }

    // ---- P -> LDS as bf16, row-major [query][key], row-XOR swizzle
    u16* pl = &Pl[wv][0];
#pragma unroll
    for (int nt = 0; nt < 4; nt++) {
        const int q = nt * 16 + c16;
        const int sw = (q & 7) << 3;
#pragma unroll
        for (int mt = 0; mt < 4; mt++) {
            const u32 p01 = (u32)f2bf(acc[mt][nt][0]) | ((u32)f2bf(acc[mt][nt][1]) << 16);
            const u32 p23 = (u32)f2bf(acc[mt][nt][2]) | ((u32)f2bf(acc[mt][nt][3]) << 16);
            *(uint2*)&pl[(q * 64 + mt * 16 + quad * 4) ^ sw] = make_uint2(p01, p23);
        }
    }
    __syncthreads();   // covers Vt writes and P writes before fragment reads

    // ---- O^T = V^T * P^T : D row = d (quad*4+r), col = query (c16)
    f32x4 o[2][4];
#pragma unroll
    for (int mt = 0; mt < 2; mt++)
#pragma unroll
        for (int nt = 0; nt < 4; nt++) o[mt][nt] = (f32x4){0.f, 0.f, 0.f, 0.f};
#pragma unroll
    for (int ks = 0; ks < 2; ks++) {
        short8 va[2], pb[4];
#pragma unroll
        for (int mt = 0; mt < 2; mt++) {
            const int d = mt * 16 + c16;
            va[mt] = *(const short8*)&vt[(d * 64 + ks * 32 + quad * 8)
                        ^ ((d & 7) << 3) ^ (((d >> 3) & 3) << 4)];
        }
#pragma unroll
        for (int nt = 0; nt < 4; nt++) {
            const int q = nt * 16 + c16;
            pb[nt] = *(const short8*)&pl[(q * 64 + ks * 32 + quad * 8) ^ ((q & 7) << 3)];
        }
#pragma unroll
        for (int mt = 0; mt < 2; mt++)
#pragma unroll
            for (int nt = 0; nt < 4; nt++)
                o[mt][nt] = __builtin_amdgcn_mfma_f32_16x16x32_bf16(
                    va[mt], pb[nt], o[mt][nt], 0, 0, 0);
    }

    // ---- normalize + write ctx (bf16), rows q<49 only
#pragma unroll
    for (int nt = 0; nt < 4; nt++) {
        const int q = nt * 16 + c16;
        if (q < NTOK) {
            u16* crow = ctx + ((size_t)wi * NTOK + q) * CDIM + h * HDIM;
#pragma unroll
            for (int mt = 0; mt < 2; mt++) {
                const u32 p01 = (u32)f2bf(o[mt][nt][0] * inv[nt])
                              | ((u32)f2bf(o[mt][nt][1] * inv[nt]) << 16);
                const u32 p23 = (u32)f2bf(o[mt][nt][2] * inv[nt])
                              | ((u32)f2bf(o[mt][nt][3] * inv[nt]) << 16);
                *(uint2*)(crow + mt * 16 + quad * 4) = make_uint2(p01, p23);
            }
        }
    }
}

extern "C" void kernel_launch(void* const* d_in, const int* in_sizes, int n_in,
                              void* d_out, int out_size, void* d_ws, size_t ws_size,
                              hipStream_t stream)
{
    (void)in_sizes; (void)n_in; (void)out_size; (void)ws_size;
    const float* x     = (const float*)d_in[0];
    const float* n1g   = (const float*)d_in[2];
    const float* n1b   = (const float*)d_in[3];
    const float* qkvw  = (const float*)d_in[4];
    const float* qkvb  = (const float*)d_in[5];
    const float* rpb   = (const float*)d_in[6];
    const float* projw = (const float*)d_in[7];
    const float* projb = (const float*)d_in[8];
    const float* n2g   = (const float*)d_in[9];
    const float* n2b   = (const float*)d_in[10];
    const float* fc1w  = (const float*)d_in[11];
    const float* fc1b  = (const float*)d_in[12];
    const float* fc2w  = (const float*)d_in[13];
    const float* fc2b  = (const float*)d_in[14];
    float* out = (float*)d_out;   // doubles as Y (x + attn residual) scratch

    char* ws = (char*)d_ws;
    const size_t szA   = (size_t)MROWS * CDIM * 2;   // 77,070,336
    const size_t szQKV = 3 * szA;                    // 231,211,008
    u16*   Abuf = (u16*)ws;
    u16*   QKV  = (u16*)(ws + szA);
    u16*   Ctx  = (u16*)(ws + szA + szQKV);
    u16*   qkvT = (u16*)(ws + szA + szQKV + szA);
    u16*   projT = qkvT + 1152 * 384;
    u16*   fc1T  = projT + 384 * 384;
    u16*   fc2T  = fc1T + 1536 * 384;
    float* btab  = (float*)(fc2T + 1536 * 384);      // 4*12*4096 f32 = 786,432 B
    u16*   H2   = Abuf;
    u16*   Mid  = QKV;

    k_conv<<<(384 * 1152 + 255) / 256, 256, 0, stream>>>(qkvw, qkvT, 384, 1152);
    k_conv<<<(384 * 384 + 255) / 256, 256, 0, stream>>>(projw, projT, 384, 384);
    k_conv<<<(384 * 1536 + 255) / 256, 256, 0, stream>>>(fc1w, fc1T, 384, 1536);
    k_conv<<<(1536 * 384 + 255) / 256, 256, 0, stream>>>(fc2w, fc2T, 1536, 384);
    k_btab<<<(4 * NHEADS * 4096) / 256, 256, 0, stream>>>(rpb, btab);

    k_ln1<<<MROWS / 4, 256, 0, stream>>>(x, n1g, n1b, Abuf);
    {
        dim3 g(MROWS / 128, 1152 / 128);
        k_mgemm<0><<<g, 256, 0, stream>>>(Abuf, qkvT, qkvb, QKV, nullptr, nullptr, MROWS, 1152, 384);
    }
    k_attn2<<<(BNWIN * NHEADS) / AW, 64 * AW, 0, stream>>>(QKV, btab, Ctx);
    {
        dim3 g(MROWS / 128, 384 / 128);
        k_mgemm<1><<<g, 256, 0, stream>>>(Ctx, projT, projb, nullptr, x, out, MROWS, 384, 384);
    }
    k_ln2<<<MROWS / 4, 256, 0, stream>>>(out, n2g, n2b, H2);
    {
        dim3 g(MROWS / 128, 1536 / 128);
        k_mgemm<2><<<g, 256, 0, stream>>>(H2, fc1T, fc1b, Mid, nullptr, nullptr, MROWS, 1536, 384);
    }
    {
        dim3 g(MROWS / 128, 384 / 128);
        k_mgemm<3><<<g, 256, 0, stream>>>(Mid, fc2T, fc2b, nullptr, out, out, MROWS, 384, 1536);
    }
}

// Round 2
// 1322.092 us; speedup vs baseline: 1.2949x; 1.0833x over previous
//
#include <hip/hip_runtime.h>
#include <stdint.h>
#include <math.h>

typedef unsigned short u16;
typedef unsigned int u32;
using short8 = __attribute__((ext_vector_type(8))) short;
using f32x4  = __attribute__((ext_vector_type(4))) float;

#define NHEADS 12
#define NTOK 49
#define CDIM 384
#define HIDDIM 1536
#define HDIM 32
#define BNWIN 2048                 // 32 batches * 64 windows
#define MROWS 100352               // BNWIN * NTOK
#define QKV_STRIDE ((size_t)BNWIN * NHEADS * NTOK * HDIM)   // 38535168 elems
#define ATT_SCALE 0.17677669529663687f
#define AW 4                       // waves per attention block

__device__ __forceinline__ float bf2f(u16 u) {
    union { unsigned int i; float f; } z; z.i = ((unsigned int)u) << 16; return z.f;
}
__device__ __forceinline__ u16 f2bf(float f) {
    union { float f; unsigned int i; } z; z.f = f;
    unsigned int i = z.i;
    i += 0x7FFFu + ((i >> 16) & 1u);   // round-to-nearest-even
    return (u16)(i >> 16);
}
__device__ __forceinline__ float lo16(u32 u) {
    union { u32 i; float f; } z; z.i = u << 16; return z.f;
}
__device__ __forceinline__ float hi16(u32 u) {
    union { u32 i; float f; } z; z.i = u & 0xffff0000u; return z.f;
}

__device__ __forceinline__ void async16(const void* g, void* l) {
    __builtin_amdgcn_global_load_lds(
        (const __attribute__((address_space(1))) void*)g,
        (__attribute__((address_space(3))) void*)l, 16, 0, 0);
}

// ---------------- weight convert+transpose: B_f32[K][N] -> BT_bf16[N][K] -------
__global__ __launch_bounds__(256) void k_conv(const float* __restrict__ B,
    u16* __restrict__ BT, int K, int N)
{
    const int idx = blockIdx.x * 256 + threadIdx.x;
    if (idx >= K * N) return;
    const int n = idx / K, k = idx - n * K;
    BT[idx] = f2bf(B[(size_t)k * N + n]);
}

// ---------------- bias+mask table in MFMA D-fragment layout --------------------
// layout: [cls(4)][head(12)][tile mt*4+nt (16)][lane (64)][reg r (4)] f32
//   key  = mt*16 + (lane>>4)*4 + r   (S^T row)
//   query= nt*16 + (lane&15)         (S^T col)
// key>=49 -> -1e30 (pad mask), query>=49 -> 0 (discarded)
__global__ __launch_bounds__(256) void k_btab(const float* __restrict__ rpb,
    float* __restrict__ bt)
{
    const int idx = blockIdx.x * 256 + threadIdx.x;   // < 4*12*4096 = 196608
    const int r    = idx & 3;
    const int lane = (idx >> 2) & 63;
    const int tile = (idx >> 8) & 15;
    const int h    = (idx >> 12) % NHEADS;
    const int cls  = idx / (NHEADS << 12);
    const int mt = tile >> 2, nt = tile & 3;
    const int kt = mt * 16 + (lane >> 4) * 4 + r;
    const int qt = nt * 16 + (lane & 15);
    float val;
    if (kt >= NTOK) val = -1e30f;
    else if (qt >= NTOK) val = 0.f;
    else {
        const int pk = kt / 7, qk = kt % 7, pq = qt / 7, qq = qt % 7;
        val = rpb[((pq - pk + 6) * 13 + (qq - qk + 6)) * NHEADS + h];
        const int ae = cls >> 1, be = cls & 1;
        const int regq = (ae ? ((pq < 4) ? 1 : 2) : 0) * 3 + (be ? ((qq < 4) ? 1 : 2) : 0);
        const int regk = (ae ? ((pk < 4) ? 1 : 2) : 0) * 3 + (be ? ((qk < 4) ? 1 : 2) : 0);
        if (regq != regk) val -= 100.f;
    }
    bt[idx] = val;
}

// ---------------- LN1 + roll(-3,-3) + window partition (gather) ----------------
__global__ __launch_bounds__(256) void k_ln1(const float* __restrict__ x,
    const float* __restrict__ g, const float* __restrict__ b, u16* __restrict__ outw)
{
    const int lane = threadIdx.x & 63;
    const int t = blockIdx.x * 4 + (threadIdx.x >> 6);     // 0..100351
    const int wi = t / NTOK, n = t % NTOK;
    const int bb = wi >> 6, w64 = wi & 63;
    const int p = (w64 >> 3) * 7 + n / 7;
    const int q = (w64 & 7) * 7 + n % 7;
    const int sh = (p + 3) % 56, sw = (q + 3) % 56;        // roll by -3
    const float* row = x + ((size_t)bb * 3136 + sh * 56 + sw) * CDIM;
    float v[6]; float s = 0.f, sq = 0.f;
#pragma unroll
    for (int i = 0; i < 6; i++) {
        v[i] = row[lane + 64 * i];
        s += v[i]; sq += v[i] * v[i];
    }
#pragma unroll
    for (int off = 32; off >= 1; off >>= 1) {
        s  += __shfl_xor(s, off, 64);
        sq += __shfl_xor(sq, off, 64);
    }
    const float mean = s * (1.f / CDIM);
    const float var  = sq * (1.f / CDIM) - mean * mean;
    const float rstd = rsqrtf(var + 1e-5f);
    u16* orow = outw + (size_t)t * CDIM;
#pragma unroll
    for (int i = 0; i < 6; i++) {
        const int c = lane + 64 * i;
        orow[c] = f2bf((v[i] - mean) * rstd * g[c] + b[c]);
    }
}

// ---------------- LN2 (straight rows, fp32 input from d_out, bf16 out) ---------
__global__ __launch_bounds__(256) void k_ln2(const float* __restrict__ y,
    const float* __restrict__ g, const float* __restrict__ b, u16* __restrict__ outw)
{
    const int lane = threadIdx.x & 63;
    const int t = blockIdx.x * 4 + (threadIdx.x >> 6);
    const float* row = y + (size_t)t * CDIM;
    float v[6]; float s = 0.f, sq = 0.f;
#pragma unroll
    for (int i = 0; i < 6; i++) {
        v[i] = row[lane + 64 * i];
        s += v[i]; sq += v[i] * v[i];
    }
#pragma unroll
    for (int off = 32; off >= 1; off >>= 1) {
        s  += __shfl_xor(s, off, 64);
        sq += __shfl_xor(sq, off, 64);
    }
    const float mean = s * (1.f / CDIM);
    const float var  = sq * (1.f / CDIM) - mean * mean;
    const float rstd = rsqrtf(var + 1e-5f);
    u16* orow = outw + (size_t)t * CDIM;
#pragma unroll
    for (int i = 0; i < 6; i++) {
        const int c = lane + 64 * i;
        orow[c] = f2bf((v[i] - mean) * rstd * g[c] + b[c]);
    }
}

// ---------------- MFMA GEMM: C = A_bf16(MxK) * BT_bf16(N x K)^T + bias ---------
// Triple-buffered 2-deep prefetch, counted vmcnt + raw barrier (never drain to 0
// in the main loop). 1D grid; bijective XCD-chunk swizzle with nb-inner tile
// order so consecutive tiles in a chunk share the A-panel (L2 reuse).
template<int MODE>
__global__ __launch_bounds__(256) void k_mgemm(
    const u16* __restrict__ A, const u16* __restrict__ BT,
    const float* __restrict__ bias,
    u16* __restrict__ out_bf,
    const float* res_f,
    float* out_f,
    int M, int Nn, int K, int NB)
{
    __shared__ __align__(16) u16 Als[3][128 * 32];
    __shared__ __align__(16) u16 Bls[3][128 * 32];
    const int tid = threadIdx.x;
    const int w = tid >> 6, l = tid & 63;
    const int wr = w >> 1, wc = w & 1;
    const int lrow = l & 15, quad = l >> 4;

    // bijective XCD chunk swizzle (m204), nb-inner tile order
    const int nwg = gridDim.x;
    const int qd = nwg >> 3, rr = nwg & 7;
    const int xcd = blockIdx.x & 7, rk = blockIdx.x >> 3;
    const int swz = ((xcd < rr) ? xcd * (qd + 1) : rr * (qd + 1) + (xcd - rr) * qd) + rk;
    const int mb = swz / NB, nb = swz - mb * NB;
    const int m0 = mb * 128, n0 = nb * 128;

    const int seg0 = tid, seg1 = tid + 256;
    const int r0 = seg0 >> 2, q0 = (seg0 & 3) ^ ((r0 >> 1) & 3);
    const int r1 = seg1 >> 2, q1 = (seg1 & 3) ^ ((r1 >> 1) & 3);
    const u16* Ag0 = A  + (size_t)(m0 + r0) * K + q0 * 8;
    const u16* Ag1 = A  + (size_t)(m0 + r1) * K + q1 * 8;
    const u16* Bg0 = BT + (size_t)(n0 + r0) * K + q0 * 8;
    const u16* Bg1 = BT + (size_t)(n0 + r1) * K + q1 * 8;

    // lane-dependent LDS byte offsets (within one buffer)
    int aoff[4], boff[4];
#pragma unroll
    for (int i = 0; i < 4; i++) {
        const int ra = wr * 64 + i * 16 + lrow;
        aoff[i] = ra * 32 + ((quad ^ ((ra >> 1) & 3)) << 3);
        const int rb = wc * 64 + i * 16 + lrow;
        boff[i] = rb * 32 + ((quad ^ ((rb >> 1) & 3)) << 3);
    }

    f32x4 acc[4][4];
#pragma unroll
    for (int i = 0; i < 4; i++)
#pragma unroll
        for (int j = 0; j < 4; j++)
            acc[i][j] = (f32x4){0.f, 0.f, 0.f, 0.f};

    auto stage = [&](int buf, int k0) {
        u16* Ald = &Als[buf][0];
        u16* Bld = &Bls[buf][0];
        async16(Ag0 + k0, Ald + seg0 * 8);
        async16(Ag1 + k0, Ald + seg1 * 8);
        async16(Bg0 + k0, Bld + seg0 * 8);
        async16(Bg1 + k0, Bld + seg1 * 8);
    };
    auto compute = [&](int buf) {
        const u16* Ab = &Als[buf][0];
        const u16* Bb = &Bls[buf][0];
        short8 af[4], bf[4];
#pragma unroll
        for (int i = 0; i < 4; i++) {
            af[i] = *(const short8*)(Ab + aoff[i]);
            bf[i] = *(const short8*)(Bb + boff[i]);
        }
#pragma unroll
        for (int mi = 0; mi < 4; mi++)
#pragma unroll
            for (int ni = 0; ni < 4; ni++)
                acc[mi][ni] = __builtin_amdgcn_mfma_f32_16x16x32_bf16(
                    af[mi], bf[ni], acc[mi][ni], 0, 0, 0);
    };

    const int nk = K >> 5;                 // >= 12 always here
    // prologue: 2-deep prefetch
    stage(0, 0);
    stage(1, 32);
    asm volatile("s_waitcnt vmcnt(4)" ::: "memory");   // tile 0 landed
    __builtin_amdgcn_s_barrier();
    __builtin_amdgcn_sched_barrier(0);
    int cur = 0;
    for (int t = 0; t < nk - 2; ++t) {
        stage((t + 2) % 3, (t + 2) << 5);              // issue next-next tile
        compute(cur);                                  // ds_read + MFMA on tile t
        asm volatile("s_waitcnt vmcnt(4)" ::: "memory"); // tile t+1 landed
        __builtin_amdgcn_s_barrier();
        __builtin_amdgcn_sched_barrier(0);
        cur = (cur + 1) % 3;
    }
    compute(cur);                                      // tile nk-2
    asm volatile("s_waitcnt vmcnt(0)" ::: "memory");   // tile nk-1 landed
    __builtin_amdgcn_s_barrier();
    __builtin_amdgcn_sched_barrier(0);
    compute((cur + 1) % 3);                            // tile nk-1

    const int mbase = m0 + wr * 64 + quad * 4;
    const int nbase = n0 + wc * 64 + lrow;
#pragma unroll
    for (int mi = 0; mi < 4; mi++) {
#pragma unroll
        for (int r = 0; r < 4; r++) {
            const int grow = mbase + mi * 16 + r;
            if constexpr (MODE == 0) {
                const int wi = grow / NTOK, n = grow % NTOK;
#pragma unroll
                for (int ni = 0; ni < 4; ni++) {
                    const int gcol = nbase + ni * 16;
                    float val = acc[mi][ni][r] + bias[gcol];
                    const int part = gcol / CDIM;
                    const int rem = gcol % CDIM;
                    const int hcol = rem >> 5, d = rem & 31;
                    if (part == 0) val *= ATT_SCALE;
                    out_bf[(size_t)part * QKV_STRIDE +
                           (((size_t)wi * NHEADS + hcol) * NTOK + n) * HDIM + d] = f2bf(val);
                }
            } else if constexpr (MODE == 1) {
                const int wi = grow / NTOK, n = grow % NTOK;
                const int bb = wi >> 6, w64 = wi & 63;
                const int p = (w64 >> 3) * 7 + n / 7;
                const int q = (w64 & 7) * 7 + n % 7;
                const int sh = (p + 3) % 56, sw = (q + 3) % 56;
                const size_t drow = ((size_t)bb * 3136 + sh * 56 + sw) * CDIM;
#pragma unroll
                for (int ni = 0; ni < 4; ni++) {
                    const int gcol = nbase + ni * 16;
                    out_f[drow + gcol] = res_f[drow + gcol] + acc[mi][ni][r] + bias[gcol];
                }
            } else if constexpr (MODE == 2) {
#pragma unroll
                for (int ni = 0; ni < 4; ni++) {
                    const int gcol = nbase + ni * 16;
                    const float v = acc[mi][ni][r] + bias[gcol];
                    const float gel = 0.5f * v * (1.0f + erff(v * 0.70710678118654752f));
                    out_bf[(size_t)grow * Nn + gcol] = f2bf(gel);
                }
            } else {  // MODE 3
#pragma unroll
                for (int ni = 0; ni < 4; ni++) {
                    const int gcol = nbase + ni * 16;
                    const size_t o = (size_t)grow * Nn + gcol;
                    out_f[o] = acc[mi][ni][r] + bias[gcol] + res_f[o];
                }
            }
        }
    }
}

// ---------------- MFMA windowed attention ---------------------------------------
// One wave per (window, head); AW waves/block. 49 tokens padded to 64.
// S^T = mfma(K, Q) with bias+mask table as C-in (table pre-masks key padding).
// Softmax over keys = 16 in-lane values + 2 shfl_xor per query group.
// O^T = mfma(V^T, P^T): V transposed+zero-padded into swizzled LDS, P bounced
// through swizzled LDS as bf16.
// LDS/wave: Vt 4KB + P 8KB -> 48KB/block -> 3 blocks/CU (12 waves/CU).
__global__ __launch_bounds__(64 * AW) void k_attn2(
    const u16* __restrict__ qkv, const float* __restrict__ btab,
    u16* __restrict__ ctx)
{
    __shared__ __align__(16) u16 Vt[AW][2048];   // V^T [d=32][key=64], swizzled
    __shared__ __align__(16) u16 Pl[AW][4096];   // P  [q=64][key=64], swizzled

    const int wv = threadIdx.x >> 6, lane = threadIdx.x & 63;
    const int quad = lane >> 4, c16 = lane & 15;
    const int gwh = blockIdx.x * AW + wv;        // 0..24575 == wi*12 + h
    const int wi = gwh / NHEADS, h = gwh - wi * NHEADS;
    const u16* qb = qkv + (size_t)gwh * (NTOK * HDIM);
    const u16* kb = qb + QKV_STRIDE;
    const u16* vb = qb + 2 * QKV_STRIDE;

    // ---- stage V transposed + zero-padded (keys 49..63 -> 0) into swizzled LDS
    u16* vt = &Vt[wv][0];
    for (int i = lane; i < 256; i += 64) {
        const int tok = i >> 2, d0 = (i & 3) * 8;
        uint4 t = make_uint4(0u, 0u, 0u, 0u);
        if (tok < NTOK) t = *(const uint4*)(vb + tok * HDIM + d0);
        const u32 w_[4] = { t.x, t.y, t.z, t.w };
#pragma unroll
        for (int j = 0; j < 8; j++) {
            const int d = d0 + j;
            const u16 val = (u16)((j & 1) ? (w_[j >> 1] >> 16) : (w_[j >> 1] & 0xffffu));
            vt[(d * 64 + tok) ^ ((d & 7) << 3) ^ (((d >> 3) & 3) << 4)] = val;
        }
    }

    // ---- Q,K fragments direct from global (rows >=49 read neighbor data; masked)
    short8 qf[4], kf[4];
#pragma unroll
    for (int t = 0; t < 4; t++) {
        qf[t] = *(const short8*)(qb + (t * 16 + c16) * HDIM + quad * 8);
        kf[t] = *(const short8*)(kb + (t * 16 + c16) * HDIM + quad * 8);
    }

    // ---- bias+mask table slice (fragment-layout, used as MFMA C-in)
    const int a = (wi & 63) >> 3, b = wi & 7;
    const int cls = ((a == 7) ? 2 : 0) | ((b == 7) ? 1 : 0);
    const f32x4* tb = (const f32x4*)(btab + ((size_t)(cls * NHEADS + h) << 12));

    // ---- S^T = K * Q^T + (bias+mask): D row = key (quad*4+r), col = query (c16)
    f32x4 acc[4][4];
#pragma unroll
    for (int mt = 0; mt < 4; mt++)
#pragma unroll
        for (int nt = 0; nt < 4; nt++)
            acc[mt][nt] = __builtin_amdgcn_mfma_f32_16x16x32_bf16(
                kf[mt], qf[nt], tb[(mt * 4 + nt) * 64 + lane], 0, 0, 0);

    // ---- softmax over keys (rows of S^T): in-lane (4 mt * 4 r) + quads via shfl
    float inv[4];
#pragma unroll
    for (int nt = 0; nt < 4; nt++) {
        float m = -1e30f;
#pragma unroll
        for (int mt = 0; mt < 4; mt++)
#pragma unroll
            for (int r = 0; r < 4; r++) m = fmaxf(m, acc[mt][nt][r]);
        m = fmaxf(m, __shfl_xor(m, 16, 64));
        m = fmaxf(m, __shfl_xor(m, 32, 64));
        float s = 0.f;
#pragma unroll
        for (int mt = 0; mt < 4; mt++)
#pragma unroll
            for (int r = 0; r < 4; r++) {
                const float e = __expf(acc[mt][nt][r] - m);
                acc[mt][nt][r] = e;
                s += e;
            }
        s += __shfl_xor(s, 16, 64);
        s += __shfl_xor(s, 32, 64);
        inv[nt] = 1.f / s;
    }

    // ---- P -> LDS as bf16, row-major [query][key], row-XOR swizzle
    u16* pl = &Pl[wv][0];
#pragma unroll
    for (int nt = 0; nt < 4; nt++) {
        const int q = nt * 16 + c16;
        const int sw = (q & 7) << 3;
#pragma unroll
        for (int mt = 0; mt < 4; mt++) {
            const u32 p01 = (u32)f2bf(acc[mt][nt][0]) | ((u32)f2bf(acc[mt][nt][1]) << 16);
            const u32 p23 = (u32)f2bf(acc[mt][nt][2]) | ((u32)f2bf(acc[mt][nt][3]) << 16);
            *(uint2*)&pl[(q * 64 + mt * 16 + quad * 4) ^ sw] = make_uint2(p01, p23);
        }
    }
    __syncthreads();   // covers Vt writes and P writes before fragment reads

    // ---- O^T = V^T * P^T : D row = d (quad*4+r), col = query (c16)
    f32x4 o[2][4];
#pragma unroll
    for (int mt = 0; mt < 2; mt++)
#pragma unroll
        for (int nt = 0; nt < 4; nt++) o[mt][nt] = (f32x4){0.f, 0.f, 0.f, 0.f};
#pragma unroll
    for (int ks = 0; ks < 2; ks++) {
        short8 va[2], pb[4];
#pragma unroll
        for (int mt = 0; mt < 2; mt++) {
            const int d = mt * 16 + c16;
            va[mt] = *(const short8*)&vt[(d * 64 + ks * 32 + quad * 8)
                        ^ ((d & 7) << 3) ^ (((d >> 3) & 3) << 4)];
        }
#pragma unroll
        for (int nt = 0; nt < 4; nt++) {
            const int q = nt * 16 + c16;
            pb[nt] = *(const short8*)&pl[(q * 64 + ks * 32 + quad * 8) ^ ((q & 7) << 3)];
        }
#pragma unroll
        for (int mt = 0; mt < 2; mt++)
#pragma unroll
            for (int nt = 0; nt < 4; nt++)
                o[mt][nt] = __builtin_amdgcn_mfma_f32_16x16x32_bf16(
                    va[mt], pb[nt], o[mt][nt], 0, 0, 0);
    }

    // ---- normalize + write ctx (bf16), rows q<49 only
#pragma unroll
    for (int nt = 0; nt < 4; nt++) {
        const int q = nt * 16 + c16;
        if (q < NTOK) {
            u16* crow = ctx + ((size_t)wi * NTOK + q) * CDIM + h * HDIM;
#pragma unroll
            for (int mt = 0; mt < 2; mt++) {
                const u32 p01 = (u32)f2bf(o[mt][nt][0] * inv[nt])
                              | ((u32)f2bf(o[mt][nt][1] * inv[nt]) << 16);
                const u32 p23 = (u32)f2bf(o[mt][nt][2] * inv[nt])
                              | ((u32)f2bf(o[mt][nt][3] * inv[nt]) << 16);
                *(uint2*)(crow + mt * 16 + quad * 4) = make_uint2(p01, p23);
            }
        }
    }
}

extern "C" void kernel_launch(void* const* d_in, const int* in_sizes, int n_in,
                              void* d_out, int out_size, void* d_ws, size_t ws_size,
                              hipStream_t stream)
{
    (void)in_sizes; (void)n_in; (void)out_size; (void)ws_size;
    const float* x     = (const float*)d_in[0];
    const float* n1g   = (const float*)d_in[2];
    const float* n1b   = (const float*)d_in[3];
    const float* qkvw  = (const float*)d_in[4];
    const float* qkvb  = (const float*)d_in[5];
    const float* rpb   = (const float*)d_in[6];
    const float* projw = (const float*)d_in[7];
    const float* projb = (const float*)d_in[8];
    const float* n2g   = (const float*)d_in[9];
    const float* n2b   = (const float*)d_in[10];
    const float* fc1w  = (const float*)d_in[11];
    const float* fc1b  = (const float*)d_in[12];
    const float* fc2w  = (const float*)d_in[13];
    const float* fc2b  = (const float*)d_in[14];
    float* out = (float*)d_out;   // doubles as Y (x + attn residual) scratch

    char* ws = (char*)d_ws;
    const size_t szA   = (size_t)MROWS * CDIM * 2;   // 77,070,336
    const size_t szQKV = 3 * szA;                    // 231,211,008
    u16*   Abuf = (u16*)ws;
    u16*   QKV  = (u16*)(ws + szA);
    u16*   Ctx  = (u16*)(ws + szA + szQKV);
    u16*   qkvT = (u16*)(ws + szA + szQKV + szA);
    u16*   projT = qkvT + 1152 * 384;
    u16*   fc1T  = projT + 384 * 384;
    u16*   fc2T  = fc1T + 1536 * 384;
    float* btab  = (float*)(fc2T + 1536 * 384);      // 4*12*4096 f32 = 786,432 B
    u16*   H2   = Abuf;
    u16*   Mid  = QKV;

    k_conv<<<(384 * 1152 + 255) / 256, 256, 0, stream>>>(qkvw, qkvT, 384, 1152);
    k_conv<<<(384 * 384 + 255) / 256, 256, 0, stream>>>(projw, projT, 384, 384);
    k_conv<<<(384 * 1536 + 255) / 256, 256, 0, stream>>>(fc1w, fc1T, 384, 1536);
    k_conv<<<(1536 * 384 + 255) / 256, 256, 0, stream>>>(fc2w, fc2T, 1536, 384);
    k_btab<<<(4 * NHEADS * 4096) / 256, 256, 0, stream>>>(rpb, btab);

    k_ln1<<<MROWS / 4, 256, 0, stream>>>(x, n1g, n1b, Abuf);
    {
        const int nb = 1152 / 128;
        k_mgemm<0><<<(MROWS / 128) * nb, 256, 0, stream>>>(Abuf, qkvT, qkvb, QKV, nullptr, nullptr, MROWS, 1152, 384, nb);
    }
    k_attn2<<<(BNWIN * NHEADS) / AW, 64 * AW, 0, stream>>>(QKV, btab, Ctx);
    {
        const int nb = 384 / 128;
        k_mgemm<1><<<(MROWS / 128) * nb, 256, 0, stream>>>(Ctx, projT, projb, nullptr, x, out, MROWS, 384, 384, nb);
    }
    k_ln2<<<MROWS / 4, 256, 0, stream>>>(out, n2g, n2b, H2);
    {
        const int nb = 1536 / 128;
        k_mgemm<2><<<(MROWS / 128) * nb, 256, 0, stream>>>(H2, fc1T, fc1b, Mid, nullptr, nullptr, MROWS, 1536, 384, nb);
    }
    {
        const int nb = 384 / 128;
        k_mgemm<3><<<(MROWS / 128) * nb, 256, 0, stream>>>(Mid, fc2T, fc2b, nullptr, out, out, MROWS, 384, 1536, nb);
    }
}